// Round 4
// baseline (90.341 us; speedup 1.0000x reference)
//
#include <hip/hip_runtime.h>
#include <hip/hip_fp16.h>

#define W 512
#define H 512
#define NSTEPS 256
#define D 256
#define DM1 255.0f
#define QUAD_WS_BYTES (256ull*256ull*256ull*8ull)   // 128 MB fp16-quad volume

struct SetupOut {
    float Rw[9];
    float src[3];
    float kinv[9];
    float sdd;
    float org[3];
    float invsp[3];
};

__device__ __forceinline__ void mat4mul(const float* A, const float* B, float* C) {
    #pragma unroll
    for (int i = 0; i < 4; ++i)
        #pragma unroll
        for (int j = 0; j < 4; ++j) {
            float s = 0.f;
            #pragma unroll
            for (int k = 0; k < 4; ++k) s += A[i*4+k] * B[k*4+j];
            C[i*4+j] = s;
        }
}

__device__ void compute_setup(const float* rt_inv, const float* k_inv, const float* sdd,
                              const float* isocenter, const float* origin, const float* spacing,
                              const float* rot, const float* xyz, SetupOut* o) {
    // --- so3_exp_map ---
    float wx = rot[0], wy = rot[1], wz = rot[2];
    float th2 = wx*wx + wy*wy + wz*wz;
    float th = sqrtf(th2 + 1e-30f);
    float a, b;
    if (th2 > 1e-8f) { a = sinf(th) / th; b = (1.f - cosf(th)) / th2; }
    else             { a = 1.f - th2 / 6.f; b = 0.5f - th2 / 24.f; }
    float K[9]  = {0.f,-wz,wy,  wz,0.f,-wx,  -wy,wx,0.f};
    float K2[9];
    #pragma unroll
    for (int i = 0; i < 3; ++i)
        #pragma unroll
        for (int j = 0; j < 3; ++j) {
            float s = 0.f;
            #pragma unroll
            for (int k = 0; k < 3; ++k) s += K[i*3+k] * K[k*3+j];
            K2[i*3+j] = s;
        }
    float R[9];
    #pragma unroll
    for (int i = 0; i < 9; ++i) R[i] = ((i % 4 == 0) ? 1.f : 0.f) + a*K[i] + b*K2[i];
    float t[3];
    #pragma unroll
    for (int i = 0; i < 3; ++i)
        t[i] = R[i*3+0]*xyz[0] + R[i*3+1]*xyz[1] + R[i*3+2]*xyz[2];

    // --- inv(rtm) via Gauss-Jordan with partial pivoting ---
    float A[16], Ainv[16];
    #pragma unroll
    for (int i = 0; i < 16; ++i) { A[i] = rt_inv[i]; Ainv[i] = 0.f; }
    Ainv[0] = Ainv[5] = Ainv[10] = Ainv[15] = 1.f;
    for (int c = 0; c < 4; ++c) {
        int p = c; float mx = fabsf(A[c*4+c]);
        for (int r = c+1; r < 4; ++r) { float v = fabsf(A[r*4+c]); if (v > mx) { mx = v; p = r; } }
        if (p != c) {
            for (int j = 0; j < 4; ++j) {
                float tmp = A[c*4+j];   A[c*4+j]   = A[p*4+j];   A[p*4+j]   = tmp;
                tmp = Ainv[c*4+j];      Ainv[c*4+j] = Ainv[p*4+j]; Ainv[p*4+j] = tmp;
            }
        }
        float inv = 1.f / A[c*4+c];
        for (int j = 0; j < 4; ++j) { A[c*4+j] *= inv; Ainv[c*4+j] *= inv; }
        for (int r = 0; r < 4; ++r) if (r != c) {
            float f = A[r*4+c];
            for (int j = 0; j < 4; ++j) { A[r*4+j] -= f*A[c*4+j]; Ainv[r*4+j] -= f*Ainv[c*4+j]; }
        }
    }
    float cv[3];
    #pragma unroll
    for (int i = 0; i < 3; ++i)
        cv[i] = Ainv[i*4+0]*isocenter[0] + Ainv[i*4+1]*isocenter[1]
              + Ainv[i*4+2]*isocenter[2] + Ainv[i*4+3];

    // --- pose = rtm @ (piv @ (T @ piv_inv)) ---
    float T[16]    = {R[0],R[1],R[2],t[0],  R[3],R[4],R[5],t[1],  R[6],R[7],R[8],t[2],  0,0,0,1};
    float piv[16]  = {1,0,0, cv[0],  0,1,0, cv[1],  0,0,1, cv[2],  0,0,0,1};
    float pivi[16] = {1,0,0,-cv[0],  0,1,0,-cv[1],  0,0,1,-cv[2],  0,0,0,1};
    float M1[16], M2[16], pose[16];
    mat4mul(T, pivi, M1);
    mat4mul(piv, M1, M2);
    mat4mul(rt_inv, M2, pose);

    #pragma unroll
    for (int i = 0; i < 3; ++i) {
        #pragma unroll
        for (int j = 0; j < 3; ++j) o->Rw[i*3+j] = pose[i*4+j];
        o->src[i] = pose[i*4+3];
    }
    #pragma unroll
    for (int i = 0; i < 9; ++i) o->kinv[i] = k_inv[i];
    o->sdd = sdd[0];
    #pragma unroll
    for (int i = 0; i < 3; ++i) { o->org[i] = origin[i]; o->invsp[i] = 1.f / spacing[i]; }
}

// ---------------------------------------------------------------------------
// Transposed repack: ws layout [x][z][y] (y fastest), 8B element at
// e = (x<<16)+(z<<8)+y  packing fp16 { v(x,y,z), v(x,y,z+1c), v(x,y+1c,z), v(x,y+1c,z+1c) }.
// Rays in a wave share z and span consecutive y -> gathers become ~coalesced.
// LDS 65x65 float tile (y/z halos, clamps baked) keeps both global read
// (lanes along z) and global write (lanes along y) coalesced.
// ---------------------------------------------------------------------------
__global__ __launch_bounds__(256) void repack_quad_t(const float* __restrict__ vol,
                                                     uint2* __restrict__ ws) {
    const int x  = blockIdx.x;
    const int y0 = blockIdx.y * 64;
    const int z0 = blockIdx.z * 64;
    const int t    = threadIdx.x;
    const int lane = t & 63;
    const int grp  = t >> 6;

    __shared__ float tile[65][66];   // [y][z], stride 66 -> 2-way bank alias only (free)
    const int xbase = x << 16;

    for (int r = grp; r <= 64; r += 4) {
        const int y   = min(y0 + r, D - 1);
        const int row = xbase + (y << 8);
        tile[r][lane] = vol[row + z0 + lane];
        if (lane == 0) tile[r][64] = vol[row + min(z0 + 64, D - 1)];
    }
    __syncthreads();

    for (int w = grp; w < 64; w += 4) {
        const int z = z0 + w;
        const float v00 = tile[lane][w],     v01 = tile[lane][w + 1];
        const float v10 = tile[lane + 1][w], v11 = tile[lane + 1][w + 1];
        __half2 h0 = __floats2half2_rn(v00, v01);   // y  : z, z+1
        __half2 h1 = __floats2half2_rn(v10, v11);   // y+1: z, z+1
        uint2 q;
        q.x = *reinterpret_cast<unsigned int*>(&h0);
        q.y = *reinterpret_cast<unsigned int*>(&h1);
        ws[xbase + (z << 8) + (y0 + lane)] = q;     // lanes -> consecutive y: coalesced
    }
}

// ---------------------------------------------------------------------------
// Common ray setup (direction, seglen, slab interval)
// ---------------------------------------------------------------------------
struct RayState {
    float dx, dy, dz, seglen;
    float sx, sy, sz, ox, oy, oz, ispx, ispy, ispz;
    int imin, imax;
    bool any;
};

__device__ __forceinline__ RayState ray_setup(const SetupOut& S, int ix, int iy) {
    RayState r;
    const float u = (float)ix + 0.5f;
    const float v = (float)iy + 0.5f;
    const float dcx = (S.kinv[0]*u + S.kinv[1]*v + S.kinv[2]) * S.sdd;
    const float dcy = (S.kinv[3]*u + S.kinv[4]*v + S.kinv[5]) * S.sdd;
    const float dcz = (S.kinv[6]*u + S.kinv[7]*v + S.kinv[8]) * S.sdd;
    r.dx = S.Rw[0]*dcx + S.Rw[1]*dcy + S.Rw[2]*dcz;
    r.dy = S.Rw[3]*dcx + S.Rw[4]*dcy + S.Rw[5]*dcz;
    r.dz = S.Rw[6]*dcx + S.Rw[7]*dcy + S.Rw[8]*dcz;
    r.seglen = sqrtf(r.dx*r.dx + r.dy*r.dy + r.dz*r.dz) * (1.0f / (float)NSTEPS);
    r.sx = S.src[0]; r.sy = S.src[1]; r.sz = S.src[2];
    r.ox = S.org[0]; r.oy = S.org[1]; r.oz = S.org[2];
    r.ispx = S.invsp[0]; r.ispy = S.invsp[1]; r.ispz = S.invsp[2];

    float fmin = 0.f, fmax = 1.f;
    bool empty = false;
    const float aa[3] = { (r.sx - r.ox) * r.ispx, (r.sy - r.oy) * r.ispy, (r.sz - r.oz) * r.ispz };
    const float bb[3] = { r.dx * r.ispx, r.dy * r.ispy, r.dz * r.ispz };
    #pragma unroll
    for (int k = 0; k < 3; ++k) {
        if (fabsf(bb[k]) > 1e-12f) {
            const float rcp = 1.f / bb[k];
            const float t0 = (0.f - aa[k]) * rcp;
            const float t1 = (DM1 - aa[k]) * rcp;
            fmin = fmaxf(fmin, fminf(t0, t1));
            fmax = fminf(fmax, fmaxf(t0, t1));
        } else if (aa[k] < 0.f || aa[k] > DM1) {
            empty = true;
        }
    }
    r.any = !empty && (fmax >= fmin);
    r.imin = max(0,          (int)floorf(fmin * (float)NSTEPS - 0.5f) - 1);
    r.imax = min(NSTEPS - 1, (int)ceilf (fmax * (float)NSTEPS - 0.5f) + 1);
    return r;
}

// ---------------------------------------------------------------------------
// Main raycast over transposed fp16-quad volume: 2 near-coalesced gathers/sample
// ---------------------------------------------------------------------------
__global__ __launch_bounds__(256) void drr_quad_kernel(
    const uint2* __restrict__ wsq,
    const float* __restrict__ rt_inv, const float* __restrict__ k_inv,
    const float* __restrict__ sdd, const float* __restrict__ isocenter,
    const float* __restrict__ origin, const float* __restrict__ spacing,
    const float* __restrict__ rot, const float* __restrict__ xyz,
    float* __restrict__ out)
{
    __shared__ SetupOut S;
    if (threadIdx.x == 0 && threadIdx.y == 0)
        compute_setup(rt_inv, k_inv, sdd, isocenter, origin, spacing, rot, xyz, &S);
    __syncthreads();

    const int seg = threadIdx.x & 1;
    const int iy = blockIdx.x * 32 + (threadIdx.x >> 1);   // v -> vox_y (now fastest axis)
    const int ix = blockIdx.y * 4  + threadIdx.y;          // u
    const RayState r = ray_setup(S, ix, iy);

    float acc = 0.f;
    if (r.any) {
        #pragma unroll 4
        for (int i = r.imin + seg; i <= r.imax; i += 2) {
            const float frac = ((float)i + 0.5f) * (1.0f / (float)NSTEPS);
            const float vx = (fmaf(r.dx, frac, r.sx) - r.ox) * r.ispx;
            const float vy = (fmaf(r.dy, frac, r.sy) - r.oy) * r.ispy;
            const float vz = (fmaf(r.dz, frac, r.sz) - r.oz) * r.ispz;
            const bool inside = (vx >= 0.f) && (vx <= DM1) &&
                                (vy >= 0.f) && (vy <= DM1) &&
                                (vz >= 0.f) && (vz <= DM1);
            if (inside) {
                const float px = floorf(vx), py = floorf(vy), pz = floorf(vz);
                const int x0 = (int)px, y0 = (int)py, z0 = (int)pz;
                const int x1 = min(x0 + 1, D - 1);
                const float fx = vx - px, fy = vy - py, fz = vz - pz;
                const float gx = 1.f - fx, gy = 1.f - fy, gz = 1.f - fz;

                const int e0 = (x0 << 16) + (z0 << 8) + y0;    // [x][z][y] layout
                const int e1 = e0 + ((x1 - x0) << 16);

                const uint2 q0 = wsq[e0];
                const uint2 q1 = wsq[e1];
                const float2 a0 = __half22float2(*reinterpret_cast<const __half2*>(&q0.x)); // y0: z0,z1
                const float2 a1 = __half22float2(*reinterpret_cast<const __half2*>(&q0.y)); // y1: z0,z1
                const float2 b0 = __half22float2(*reinterpret_cast<const __half2*>(&q1.x));
                const float2 b1 = __half22float2(*reinterpret_cast<const __half2*>(&q1.y));

                const float c00 = a0.x*gz + a0.y*fz;
                const float c01 = a1.x*gz + a1.y*fz;
                const float c10 = b0.x*gz + b0.y*fz;
                const float c11 = b1.x*gz + b1.y*fz;
                acc += (c00*gy + c01*fy)*gx + (c10*gy + c11*fy)*fx;
            }
        }
    }
    acc += __shfl_xor(acc, 1);
    if (seg == 0)
        out[iy * W + ix] = acc * r.seglen;
}

// ---------------------------------------------------------------------------
// Fallback: direct 8-gather path (used when ws_size < 128 MB)
// ---------------------------------------------------------------------------
__global__ __launch_bounds__(256) void drr_direct_kernel(
    const float* __restrict__ vol,
    const float* __restrict__ rt_inv, const float* __restrict__ k_inv,
    const float* __restrict__ sdd, const float* __restrict__ isocenter,
    const float* __restrict__ origin, const float* __restrict__ spacing,
    const float* __restrict__ rot, const float* __restrict__ xyz,
    float* __restrict__ out)
{
    __shared__ SetupOut S;
    if (threadIdx.x == 0 && threadIdx.y == 0)
        compute_setup(rt_inv, k_inv, sdd, isocenter, origin, spacing, rot, xyz, &S);
    __syncthreads();

    const int seg = threadIdx.x & 1;
    const int iy = blockIdx.x * 32 + (threadIdx.x >> 1);
    const int ix = blockIdx.y * 4  + threadIdx.y;
    const RayState r = ray_setup(S, ix, iy);

    float acc = 0.f;
    if (r.any) {
        #pragma unroll 4
        for (int i = r.imin + seg; i <= r.imax; i += 2) {
            const float frac = ((float)i + 0.5f) * (1.0f / (float)NSTEPS);
            const float vx = (fmaf(r.dx, frac, r.sx) - r.ox) * r.ispx;
            const float vy = (fmaf(r.dy, frac, r.sy) - r.oy) * r.ispy;
            const float vz = (fmaf(r.dz, frac, r.sz) - r.oz) * r.ispz;
            const bool inside = (vx >= 0.f) && (vx <= DM1) &&
                                (vy >= 0.f) && (vy <= DM1) &&
                                (vz >= 0.f) && (vz <= DM1);
            if (inside) {
                const float px = floorf(vx), py = floorf(vy), pz = floorf(vz);
                const int x0 = (int)px, y0 = (int)py, z0 = (int)pz;
                const int x1 = min(x0 + 1, D - 1);
                const int y1 = min(y0 + 1, D - 1);
                const int z1 = min(z0 + 1, D - 1);
                const float fx = vx - px, fy = vy - py, fz = vz - pz;
                const float gx = 1.f - fx, gy = 1.f - fy, gz = 1.f - fz;

                const int base = (x0 << 16) + (y0 << 8);
                const int bx = (x1 - x0) << 16;
                const int by = (y1 - y0) << 8;

                const float v000 = vol[base + z0],           v001 = vol[base + z1];
                const float v010 = vol[base + by + z0],      v011 = vol[base + by + z1];
                const float v100 = vol[base + bx + z0],      v101 = vol[base + bx + z1];
                const float v110 = vol[base + bx + by + z0], v111 = vol[base + bx + by + z1];

                const float c00 = v000*gz + v001*fz;
                const float c01 = v010*gz + v011*fz;
                const float c10 = v100*gz + v101*fz;
                const float c11 = v110*gz + v111*fz;
                acc += (c00*gy + c01*fy)*gx + (c10*gy + c11*fy)*fx;
            }
        }
    }
    acc += __shfl_xor(acc, 1);
    if (seg == 0)
        out[iy * W + ix] = acc * r.seglen;
}

extern "C" void kernel_launch(void* const* d_in, const int* in_sizes, int n_in,
                              void* d_out, int out_size, void* d_ws, size_t ws_size,
                              hipStream_t stream) {
    const float* vol      = (const float*)d_in[0];
    const float* rt_inv   = (const float*)d_in[1];
    const float* k_inv    = (const float*)d_in[2];
    const float* sdd      = (const float*)d_in[3];
    const float* iso      = (const float*)d_in[4];
    const float* origin   = (const float*)d_in[5];
    const float* spacing  = (const float*)d_in[6];
    const float* rot      = (const float*)d_in[7];
    const float* xyz      = (const float*)d_in[8];
    float* out = (float*)d_out;

    dim3 block(64, 4);
    dim3 grid(H / 32, W / 4);   // 2048 blocks = 8192 waves

    if (ws_size >= QUAD_WS_BYTES) {
        uint2* wsq = (uint2*)d_ws;
        repack_quad_t<<<dim3(D, 4, 4), 256, 0, stream>>>(vol, wsq);
        drr_quad_kernel<<<grid, block, 0, stream>>>(wsq, rt_inv, k_inv, sdd, iso,
                                                    origin, spacing, rot, xyz, out);
    } else {
        drr_direct_kernel<<<grid, block, 0, stream>>>(vol, rt_inv, k_inv, sdd, iso,
                                                      origin, spacing, rot, xyz, out);
    }
}

// Round 5
// 74.273 us; speedup vs baseline: 1.2163x; 1.2163x over previous
//
#include <hip/hip_runtime.h>
#include <hip/hip_fp16.h>

#define W 512
#define H 512
#define NSTEPS 256
#define D 256
#define DM1 255.0f
#define PAIR_WS_BYTES (256ull*256ull*256ull*4ull)   // 64 MB fp16 y-pair volume

struct SetupOut {
    float Rw[9];
    float src[3];
    float kinv[9];
    float sdd;
    float org[3];
    float invsp[3];
};

__device__ __forceinline__ void mat4mul(const float* A, const float* B, float* C) {
    #pragma unroll
    for (int i = 0; i < 4; ++i)
        #pragma unroll
        for (int j = 0; j < 4; ++j) {
            float s = 0.f;
            #pragma unroll
            for (int k = 0; k < 4; ++k) s += A[i*4+k] * B[k*4+j];
            C[i*4+j] = s;
        }
}

__device__ void compute_setup(const float* rt_inv, const float* k_inv, const float* sdd,
                              const float* isocenter, const float* origin, const float* spacing,
                              const float* rot, const float* xyz, SetupOut* o) {
    // --- so3_exp_map ---
    float wx = rot[0], wy = rot[1], wz = rot[2];
    float th2 = wx*wx + wy*wy + wz*wz;
    float th = sqrtf(th2 + 1e-30f);
    float a, b;
    if (th2 > 1e-8f) { a = sinf(th) / th; b = (1.f - cosf(th)) / th2; }
    else             { a = 1.f - th2 / 6.f; b = 0.5f - th2 / 24.f; }
    float K[9]  = {0.f,-wz,wy,  wz,0.f,-wx,  -wy,wx,0.f};
    float K2[9];
    #pragma unroll
    for (int i = 0; i < 3; ++i)
        #pragma unroll
        for (int j = 0; j < 3; ++j) {
            float s = 0.f;
            #pragma unroll
            for (int k = 0; k < 3; ++k) s += K[i*3+k] * K[k*3+j];
            K2[i*3+j] = s;
        }
    float R[9];
    #pragma unroll
    for (int i = 0; i < 9; ++i) R[i] = ((i % 4 == 0) ? 1.f : 0.f) + a*K[i] + b*K2[i];
    float t[3];
    #pragma unroll
    for (int i = 0; i < 3; ++i)
        t[i] = R[i*3+0]*xyz[0] + R[i*3+1]*xyz[1] + R[i*3+2]*xyz[2];

    // --- inv(rtm) via Gauss-Jordan with partial pivoting ---
    float A[16], Ainv[16];
    #pragma unroll
    for (int i = 0; i < 16; ++i) { A[i] = rt_inv[i]; Ainv[i] = 0.f; }
    Ainv[0] = Ainv[5] = Ainv[10] = Ainv[15] = 1.f;
    for (int c = 0; c < 4; ++c) {
        int p = c; float mx = fabsf(A[c*4+c]);
        for (int r = c+1; r < 4; ++r) { float v = fabsf(A[r*4+c]); if (v > mx) { mx = v; p = r; } }
        if (p != c) {
            for (int j = 0; j < 4; ++j) {
                float tmp = A[c*4+j];   A[c*4+j]   = A[p*4+j];   A[p*4+j]   = tmp;
                tmp = Ainv[c*4+j];      Ainv[c*4+j] = Ainv[p*4+j]; Ainv[p*4+j] = tmp;
            }
        }
        float inv = 1.f / A[c*4+c];
        for (int j = 0; j < 4; ++j) { A[c*4+j] *= inv; Ainv[c*4+j] *= inv; }
        for (int r = 0; r < 4; ++r) if (r != c) {
            float f = A[r*4+c];
            for (int j = 0; j < 4; ++j) { A[r*4+j] -= f*A[c*4+j]; Ainv[r*4+j] -= f*Ainv[c*4+j]; }
        }
    }
    float cv[3];
    #pragma unroll
    for (int i = 0; i < 3; ++i)
        cv[i] = Ainv[i*4+0]*isocenter[0] + Ainv[i*4+1]*isocenter[1]
              + Ainv[i*4+2]*isocenter[2] + Ainv[i*4+3];

    // --- pose = rtm @ (piv @ (T @ piv_inv)) ---
    float T[16]    = {R[0],R[1],R[2],t[0],  R[3],R[4],R[5],t[1],  R[6],R[7],R[8],t[2],  0,0,0,1};
    float piv[16]  = {1,0,0, cv[0],  0,1,0, cv[1],  0,0,1, cv[2],  0,0,0,1};
    float pivi[16] = {1,0,0,-cv[0],  0,1,0,-cv[1],  0,0,1,-cv[2],  0,0,0,1};
    float M1[16], M2[16], pose[16];
    mat4mul(T, pivi, M1);
    mat4mul(piv, M1, M2);
    mat4mul(rt_inv, M2, pose);

    #pragma unroll
    for (int i = 0; i < 3; ++i) {
        #pragma unroll
        for (int j = 0; j < 3; ++j) o->Rw[i*3+j] = pose[i*4+j];
        o->src[i] = pose[i*4+3];
    }
    #pragma unroll
    for (int i = 0; i < 9; ++i) o->kinv[i] = k_inv[i];
    o->sdd = sdd[0];
    #pragma unroll
    for (int i = 0; i < 3; ++i) { o->org[i] = origin[i]; o->invsp[i] = 1.f / spacing[i]; }
}

// ---------------------------------------------------------------------------
// Transposed y-pair repack: ws layout [x][z][y] (y fastest), 4B element at
// e = (x<<16)+(z<<8)+y holding fp16 { v(x,y,z), v(x,y+1c,z) }.
// No z-halo needed (pair is over y only). 128-y tile per block; each lane
// emits 2 consecutive y-elements as one uint2 -> 512B contiguous stores.
// LDS XOR-swizzle (stride 64, col ^ ((row>>1)&31)) makes both the row-write
// and the even-row-stride read conflict-free (padding cannot: read stride is
// inherently even, so any odd pad still gives 4-way).
// ---------------------------------------------------------------------------
__global__ __launch_bounds__(512) void repack_pair_t(const float* __restrict__ vol,
                                                     uint32_t* __restrict__ ws) {
    const int x  = blockIdx.x;
    const int y0 = blockIdx.y * 128;
    const int z0 = blockIdx.z * 64;
    const int lane = threadIdx.x & 63;
    const int grp  = threadIdx.x >> 6;     // 8 groups (512 threads)

    __shared__ float tf[129 * 64];         // [row 0..128][col 0..63], XOR-swizzled
    const int xbase = x << 16;

    // Phase 1: load 129 y-rows of 64 z each (coalesced 256B per wave-instr)
    for (int r = grp; r <= 128; r += 8) {
        const int y = min(y0 + r, D - 1);
        const float val = vol[xbase + (y << 8) + z0 + lane];
        tf[r * 64 + (lane ^ ((r >> 1) & 31))] = val;
    }
    __syncthreads();

    // Phase 2: for each z column, lane packs y-pair elements (2l, 2l+1)
    for (int w = grp; w < 64; w += 8) {
        const int z = z0 + w;
        const int l = lane;
        const float va = tf[(2*l    ) * 64 + (w ^ ( l      & 31))];  // v(y0+2l,   z)
        const float vb = tf[(2*l + 1) * 64 + (w ^ ( l      & 31))];  // v(y0+2l+1, z)
        const float vc = tf[(2*l + 2) * 64 + (w ^ ((l + 1) & 31))];  // v(y0+2l+2, z)
        __half2 h0 = __floats2half2_rn(va, vb);   // element y=2l:   {v(y), v(y+1)}
        __half2 h1 = __floats2half2_rn(vb, vc);   // element y=2l+1: {v(y), v(y+1)}
        uint2 q;
        q.x = *reinterpret_cast<unsigned int*>(&h0);
        q.y = *reinterpret_cast<unsigned int*>(&h1);
        // element index xbase + (z<<8) + y0 + 2l ; 512B contiguous per wave
        reinterpret_cast<uint2*>(ws + xbase + (z << 8) + y0)[l] = q;
    }
}

// ---------------------------------------------------------------------------
// Common ray setup (direction, seglen, slab interval)
// ---------------------------------------------------------------------------
struct RayState {
    float dx, dy, dz, seglen;
    float sx, sy, sz, ox, oy, oz, ispx, ispy, ispz;
    int imin, imax;
    bool any;
};

__device__ __forceinline__ RayState ray_setup(const SetupOut& S, int ix, int iy) {
    RayState r;
    const float u = (float)ix + 0.5f;
    const float v = (float)iy + 0.5f;
    const float dcx = (S.kinv[0]*u + S.kinv[1]*v + S.kinv[2]) * S.sdd;
    const float dcy = (S.kinv[3]*u + S.kinv[4]*v + S.kinv[5]) * S.sdd;
    const float dcz = (S.kinv[6]*u + S.kinv[7]*v + S.kinv[8]) * S.sdd;
    r.dx = S.Rw[0]*dcx + S.Rw[1]*dcy + S.Rw[2]*dcz;
    r.dy = S.Rw[3]*dcx + S.Rw[4]*dcy + S.Rw[5]*dcz;
    r.dz = S.Rw[6]*dcx + S.Rw[7]*dcy + S.Rw[8]*dcz;
    r.seglen = sqrtf(r.dx*r.dx + r.dy*r.dy + r.dz*r.dz) * (1.0f / (float)NSTEPS);
    r.sx = S.src[0]; r.sy = S.src[1]; r.sz = S.src[2];
    r.ox = S.org[0]; r.oy = S.org[1]; r.oz = S.org[2];
    r.ispx = S.invsp[0]; r.ispy = S.invsp[1]; r.ispz = S.invsp[2];

    float fmin = 0.f, fmax = 1.f;
    bool empty = false;
    const float aa[3] = { (r.sx - r.ox) * r.ispx, (r.sy - r.oy) * r.ispy, (r.sz - r.oz) * r.ispz };
    const float bb[3] = { r.dx * r.ispx, r.dy * r.ispy, r.dz * r.ispz };
    #pragma unroll
    for (int k = 0; k < 3; ++k) {
        if (fabsf(bb[k]) > 1e-12f) {
            const float rcp = 1.f / bb[k];
            const float t0 = (0.f - aa[k]) * rcp;
            const float t1 = (DM1 - aa[k]) * rcp;
            fmin = fmaxf(fmin, fminf(t0, t1));
            fmax = fminf(fmax, fmaxf(t0, t1));
        } else if (aa[k] < 0.f || aa[k] > DM1) {
            empty = true;
        }
    }
    r.any = !empty && (fmax >= fmin);
    r.imin = max(0,          (int)floorf(fmin * (float)NSTEPS - 0.5f) - 1);
    r.imax = min(NSTEPS - 1, (int)ceilf (fmax * (float)NSTEPS - 0.5f) + 1);
    return r;
}

// ---------------------------------------------------------------------------
// Main raycast over transposed fp16 y-pair volume:
// 4 near-coalesced dword gathers per trilinear sample (x0/x1 x z0/z1),
// each gather covers both y-corners.
// ---------------------------------------------------------------------------
__global__ __launch_bounds__(256) void drr_pair_kernel(
    const uint32_t* __restrict__ wsp,
    const float* __restrict__ rt_inv, const float* __restrict__ k_inv,
    const float* __restrict__ sdd, const float* __restrict__ isocenter,
    const float* __restrict__ origin, const float* __restrict__ spacing,
    const float* __restrict__ rot, const float* __restrict__ xyz,
    float* __restrict__ out)
{
    __shared__ SetupOut S;
    if (threadIdx.x == 0 && threadIdx.y == 0)
        compute_setup(rt_inv, k_inv, sdd, isocenter, origin, spacing, rot, xyz, &S);
    __syncthreads();

    const int seg = threadIdx.x & 1;
    const int iy = blockIdx.x * 32 + (threadIdx.x >> 1);   // v -> vox_y (fastest axis)
    const int ix = blockIdx.y * 4  + threadIdx.y;          // u
    const RayState r = ray_setup(S, ix, iy);

    float acc = 0.f;
    if (r.any) {
        #pragma unroll 4
        for (int i = r.imin + seg; i <= r.imax; i += 2) {
            const float frac = ((float)i + 0.5f) * (1.0f / (float)NSTEPS);
            const float vx = (fmaf(r.dx, frac, r.sx) - r.ox) * r.ispx;
            const float vy = (fmaf(r.dy, frac, r.sy) - r.oy) * r.ispy;
            const float vz = (fmaf(r.dz, frac, r.sz) - r.oz) * r.ispz;
            const bool inside = (vx >= 0.f) && (vx <= DM1) &&
                                (vy >= 0.f) && (vy <= DM1) &&
                                (vz >= 0.f) && (vz <= DM1);
            if (inside) {
                const float px = floorf(vx), py = floorf(vy), pz = floorf(vz);
                const int x0 = (int)px, y0 = (int)py, z0 = (int)pz;
                const int x1 = min(x0 + 1, D - 1);
                const int z1 = min(z0 + 1, D - 1);
                const float fx = vx - px, fy = vy - py, fz = vz - pz;
                const float gx = 1.f - fx, gy = 1.f - fy, gz = 1.f - fz;

                const int e00 = (x0 << 16) + (z0 << 8) + y0;   // [x][z][y] layout
                const int zo  = (z1 - z0) << 8;
                const int xo  = (x1 - x0) << 16;

                const uint32_t q00 = wsp[e00];        // (x0,z0): {y0,y1}
                const uint32_t q01 = wsp[e00 + zo];   // (x0,z1)
                const uint32_t q10 = wsp[e00 + xo];   // (x1,z0)
                const uint32_t q11 = wsp[e00 + xo + zo];

                const float2 a00 = __half22float2(*reinterpret_cast<const __half2*>(&q00));
                const float2 a01 = __half22float2(*reinterpret_cast<const __half2*>(&q01));
                const float2 a10 = __half22float2(*reinterpret_cast<const __half2*>(&q10));
                const float2 a11 = __half22float2(*reinterpret_cast<const __half2*>(&q11));

                // y-interp, then z, then x
                const float m00 = a00.x*gy + a00.y*fy;   // (x0,z0)
                const float m01 = a01.x*gy + a01.y*fy;   // (x0,z1)
                const float m10 = a10.x*gy + a10.y*fy;   // (x1,z0)
                const float m11 = a11.x*gy + a11.y*fy;   // (x1,z1)
                const float c0 = m00*gz + m01*fz;
                const float c1 = m10*gz + m11*fz;
                acc += c0*gx + c1*fx;
            }
        }
    }
    acc += __shfl_xor(acc, 1);
    if (seg == 0)
        out[iy * W + ix] = acc * r.seglen;
}

// ---------------------------------------------------------------------------
// Fallback: direct 8-gather path (used when ws_size < 64 MB)
// ---------------------------------------------------------------------------
__global__ __launch_bounds__(256) void drr_direct_kernel(
    const float* __restrict__ vol,
    const float* __restrict__ rt_inv, const float* __restrict__ k_inv,
    const float* __restrict__ sdd, const float* __restrict__ isocenter,
    const float* __restrict__ origin, const float* __restrict__ spacing,
    const float* __restrict__ rot, const float* __restrict__ xyz,
    float* __restrict__ out)
{
    __shared__ SetupOut S;
    if (threadIdx.x == 0 && threadIdx.y == 0)
        compute_setup(rt_inv, k_inv, sdd, isocenter, origin, spacing, rot, xyz, &S);
    __syncthreads();

    const int seg = threadIdx.x & 1;
    const int iy = blockIdx.x * 32 + (threadIdx.x >> 1);
    const int ix = blockIdx.y * 4  + threadIdx.y;
    const RayState r = ray_setup(S, ix, iy);

    float acc = 0.f;
    if (r.any) {
        #pragma unroll 4
        for (int i = r.imin + seg; i <= r.imax; i += 2) {
            const float frac = ((float)i + 0.5f) * (1.0f / (float)NSTEPS);
            const float vx = (fmaf(r.dx, frac, r.sx) - r.ox) * r.ispx;
            const float vy = (fmaf(r.dy, frac, r.sy) - r.oy) * r.ispy;
            const float vz = (fmaf(r.dz, frac, r.sz) - r.oz) * r.ispz;
            const bool inside = (vx >= 0.f) && (vx <= DM1) &&
                                (vy >= 0.f) && (vy <= DM1) &&
                                (vz >= 0.f) && (vz <= DM1);
            if (inside) {
                const float px = floorf(vx), py = floorf(vy), pz = floorf(vz);
                const int x0 = (int)px, y0 = (int)py, z0 = (int)pz;
                const int x1 = min(x0 + 1, D - 1);
                const int y1 = min(y0 + 1, D - 1);
                const int z1 = min(z0 + 1, D - 1);
                const float fx = vx - px, fy = vy - py, fz = vz - pz;
                const float gx = 1.f - fx, gy = 1.f - fy, gz = 1.f - fz;

                const int base = (x0 << 16) + (y0 << 8);
                const int bx = (x1 - x0) << 16;
                const int by = (y1 - y0) << 8;

                const float v000 = vol[base + z0],           v001 = vol[base + z1];
                const float v010 = vol[base + by + z0],      v011 = vol[base + by + z1];
                const float v100 = vol[base + bx + z0],      v101 = vol[base + bx + z1];
                const float v110 = vol[base + bx + by + z0], v111 = vol[base + bx + by + z1];

                const float c00 = v000*gz + v001*fz;
                const float c01 = v010*gz + v011*fz;
                const float c10 = v100*gz + v101*fz;
                const float c11 = v110*gz + v111*fz;
                acc += (c00*gy + c01*fy)*gx + (c10*gy + c11*fy)*fx;
            }
        }
    }
    acc += __shfl_xor(acc, 1);
    if (seg == 0)
        out[iy * W + ix] = acc * r.seglen;
}

extern "C" void kernel_launch(void* const* d_in, const int* in_sizes, int n_in,
                              void* d_out, int out_size, void* d_ws, size_t ws_size,
                              hipStream_t stream) {
    const float* vol      = (const float*)d_in[0];
    const float* rt_inv   = (const float*)d_in[1];
    const float* k_inv    = (const float*)d_in[2];
    const float* sdd      = (const float*)d_in[3];
    const float* iso      = (const float*)d_in[4];
    const float* origin   = (const float*)d_in[5];
    const float* spacing  = (const float*)d_in[6];
    const float* rot      = (const float*)d_in[7];
    const float* xyz      = (const float*)d_in[8];
    float* out = (float*)d_out;

    dim3 block(64, 4);
    dim3 grid(H / 32, W / 4);   // 2048 blocks = 8192 waves

    if (ws_size >= PAIR_WS_BYTES) {
        uint32_t* wsp = (uint32_t*)d_ws;
        repack_pair_t<<<dim3(D, 2, 4), 512, 0, stream>>>(vol, wsp);
        drr_pair_kernel<<<grid, block, 0, stream>>>(wsp, rt_inv, k_inv, sdd, iso,
                                                    origin, spacing, rot, xyz, out);
    } else {
        drr_direct_kernel<<<grid, block, 0, stream>>>(vol, rt_inv, k_inv, sdd, iso,
                                                      origin, spacing, rot, xyz, out);
    }
}